// Round 1
// baseline (5673.673 us; speedup 1.0000x reference)
//
#include <hip/hip_runtime.h>

#define N_NODES 50000
#define N_EDGES 800000
#define D_FEAT  256
#define N_CLASS 40

// ---------------- degree ----------------
__global__ void sage_deg_kernel(const int* __restrict__ dst, float* __restrict__ deg) {
    int e = blockIdx.x * blockDim.x + threadIdx.x;
    if (e < N_EDGES) atomicAdd(&deg[dst[e]], 1.0f);
}

// ---------------- scatter-add of gathered rows ----------------
// thread t: edge e = t>>6, float4 chunk c = t&63 (64 chunks * 4 = 256 feats)
__global__ void sage_scatter_kernel(const float* __restrict__ feat,
                                    const int* __restrict__ src,
                                    const int* __restrict__ dst,
                                    float* __restrict__ agg) {
    int tid = blockIdx.x * blockDim.x + threadIdx.x;
    int e = tid >> 6;
    int c = tid & 63;
    if (e >= N_EDGES) return;
    int s = src[e];
    int d = dst[e];
    const float4 v = reinterpret_cast<const float4*>(feat + (size_t)s * D_FEAT)[c];
    float* out = agg + (size_t)d * D_FEAT + (size_t)c * 4;
    atomicAdd(out + 0, v.x);
    atomicAdd(out + 1, v.y);
    atomicAdd(out + 2, v.z);
    atomicAdd(out + 3, v.w);
}

// ---------------- mean-normalize in place ----------------
__global__ void sage_normalize_kernel(float* __restrict__ agg, const float* __restrict__ deg) {
    int tid = blockIdx.x * blockDim.x + threadIdx.x;
    int i = tid >> 6;
    int c = tid & 63;
    if (i >= N_NODES) return;
    float s = 1.0f / fmaxf(deg[i], 1.0f);
    float4* p = reinterpret_cast<float4*>(agg + (size_t)i * D_FEAT) + c;
    float4 v = *p;
    v.x *= s; v.y *= s; v.z *= s; v.w *= s;
    *p = v;
}

// ---------------- fused dual GEMM: out = relu?(A1@W1^T + A2@W2^T + bl + br) ----------------
// A1,A2: [N_NODES][256] row-major. W1,W2: [NOUT][256] row-major. Virtual K=512.
// Tiles: BM=64, BN=64, BK=16. 256 threads, 4x4 micro-tile each.
template <bool RELU, int NOUT>
__global__ __launch_bounds__(256)
void sage_gemm_kernel(const float* __restrict__ A1, const float* __restrict__ A2,
                      const float* __restrict__ W1, const float* __restrict__ W2,
                      const float* __restrict__ bl, const float* __restrict__ br,
                      float* __restrict__ out) {
    const int BM = 64, BN = 64, BK = 16;
    __shared__ __align__(16) float As[BK][BM + 4];   // row stride 272B, 16B-aligned
    __shared__ __align__(16) float Bs[BK][BN + 4];

    const int tid = threadIdx.x;
    const int tx = tid & 15;    // n dim (4 cols each)
    const int ty = tid >> 4;    // m dim (4 rows each)
    const int row0 = blockIdx.x * BM;
    const int col0 = blockIdx.y * BN;

    const int lr = tid >> 2;          // 0..63: tile row (A) / out col (B)
    const int lk = (tid & 3) * 4;     // k offset within BK: 0,4,8,12

    float acc[4][4] = {};

    for (int kt = 0; kt < 2 * D_FEAT; kt += BK) {
        const float* __restrict__ A = (kt < D_FEAT) ? A1 : A2;
        const float* __restrict__ W = (kt < D_FEAT) ? W1 : W2;
        const int kbase = kt & (D_FEAT - 1);

        // A tile load (64 rows x 16 k), transposed into As[k][m]
        {
            const int grow = row0 + lr;
            float4 av = make_float4(0.f, 0.f, 0.f, 0.f);
            if (grow < N_NODES)
                av = *reinterpret_cast<const float4*>(A + (size_t)grow * D_FEAT + kbase + lk);
            As[lk + 0][lr] = av.x;
            As[lk + 1][lr] = av.y;
            As[lk + 2][lr] = av.z;
            As[lk + 3][lr] = av.w;
        }
        // B tile load (64 out-cols x 16 k), transposed into Bs[k][n]
        {
            const int gcol = col0 + lr;
            float4 bv = make_float4(0.f, 0.f, 0.f, 0.f);
            if (gcol < NOUT)
                bv = *reinterpret_cast<const float4*>(W + (size_t)gcol * D_FEAT + kbase + lk);
            Bs[lk + 0][lr] = bv.x;
            Bs[lk + 1][lr] = bv.y;
            Bs[lk + 2][lr] = bv.z;
            Bs[lk + 3][lr] = bv.w;
        }
        __syncthreads();

        #pragma unroll
        for (int k = 0; k < BK; ++k) {
            float a[4], b[4];
            *reinterpret_cast<float4*>(a) = *reinterpret_cast<const float4*>(&As[k][ty * 4]);
            *reinterpret_cast<float4*>(b) = *reinterpret_cast<const float4*>(&Bs[k][tx * 4]);
            #pragma unroll
            for (int i = 0; i < 4; ++i)
                #pragma unroll
                for (int j = 0; j < 4; ++j)
                    acc[i][j] += a[i] * b[j];
        }
        __syncthreads();
    }

    #pragma unroll
    for (int i = 0; i < 4; ++i) {
        const int r = row0 + ty * 4 + i;
        if (r >= N_NODES) continue;
        #pragma unroll
        for (int j = 0; j < 4; ++j) {
            const int c = col0 + tx * 4 + j;
            if (c >= NOUT) continue;
            float v = acc[i][j] + bl[c] + br[c];
            if (RELU) v = fmaxf(v, 0.f);
            out[(size_t)r * NOUT + c] = v;
        }
    }
}

extern "C" void kernel_launch(void* const* d_in, const int* in_sizes, int n_in,
                              void* d_out, int out_size, void* d_ws, size_t ws_size,
                              hipStream_t stream) {
    const float* x    = (const float*)d_in[0];
    const int*   ei   = (const int*)d_in[1];      // [2][E] int
    const float* w1l  = (const float*)d_in[2];
    const float* b1l  = (const float*)d_in[3];
    const float* w1r  = (const float*)d_in[4];
    const float* b1r  = (const float*)d_in[5];
    const float* w2l  = (const float*)d_in[6];
    const float* b2l  = (const float*)d_in[7];
    const float* w2r  = (const float*)d_in[8];
    const float* b2r  = (const float*)d_in[9];
    float* out = (float*)d_out;

    const int* src = ei;
    const int* dst = ei + N_EDGES;

    // workspace layout
    const size_t AGG_OFF = 204800;                         // deg: 200KB, padded
    const size_t AGG_BYTES = (size_t)N_NODES * D_FEAT * 4; // 51.2 MB
    float* deg = (float*)d_ws;
    float* agg = (float*)((char*)d_ws + AGG_OFF);
    float* h   = (float*)((char*)d_ws + AGG_OFF + AGG_BYTES);

    const int scatter_blocks = (N_EDGES * 64) / 256;   // 200000
    const int norm_blocks    = (N_NODES * 64 + 255) / 256;
    const int mblocks        = (N_NODES + 63) / 64;    // 782

    // ---- layer 1 ----
    hipMemsetAsync(d_ws, 0, AGG_OFF + AGG_BYTES, stream);  // deg + agg
    sage_deg_kernel<<<(N_EDGES + 255) / 256, 256, 0, stream>>>(dst, deg);
    sage_scatter_kernel<<<scatter_blocks, 256, 0, stream>>>(x, src, dst, agg);
    sage_normalize_kernel<<<norm_blocks, 256, 0, stream>>>(agg, deg);
    sage_gemm_kernel<true, D_FEAT><<<dim3(mblocks, D_FEAT / 64), 256, 0, stream>>>(
        agg, x, w1l, w1r, b1l, b1r, h);

    // ---- layer 2 ----
    hipMemsetAsync(agg, 0, AGG_BYTES, stream);
    sage_scatter_kernel<<<scatter_blocks, 256, 0, stream>>>(h, src, dst, agg);
    sage_normalize_kernel<<<norm_blocks, 256, 0, stream>>>(agg, deg);
    sage_gemm_kernel<false, N_CLASS><<<dim3(mblocks, 1), 256, 0, stream>>>(
        agg, h, w2l, w2r, b2l, b2r, out);

    (void)in_sizes; (void)n_in; (void)out_size; (void)ws_size;
}

// Round 2
// 706.028 us; speedup vs baseline: 8.0360x; 8.0360x over previous
//
#include <hip/hip_runtime.h>

#define N_NODES 50000
#define N_EDGES 800000
#define D_FEAT  256
#define N_CLASS 40

// ---------------- degree histogram (into cursor array) ----------------
__global__ void sage_deg_kernel(const int* __restrict__ dst, int* __restrict__ degc) {
    int e = blockIdx.x * blockDim.x + threadIdx.x;
    if (e < N_EDGES) atomicAdd(&degc[dst[e]], 1);
}

// ---------------- single-workgroup exclusive scan ----------------
// deg_cursor holds degrees on entry; on exit it holds the exclusive prefix
// (serving as the CSR fill cursor). row_off gets the same prefix + total at [N].
__global__ __launch_bounds__(1024)
void sage_scan_kernel(int* __restrict__ deg_cursor, int* __restrict__ row_off) {
    __shared__ int partial[1024];
    const int tid = threadIdx.x;
    const int PER = (N_NODES + 1023) / 1024;   // 49
    const int base = tid * PER;

    int sum = 0;
    for (int i = 0; i < PER; ++i) {
        int idx = base + i;
        if (idx < N_NODES) sum += deg_cursor[idx];
    }
    partial[tid] = sum;
    __syncthreads();
    // Hillis-Steele inclusive scan over 1024 partials
    for (int off = 1; off < 1024; off <<= 1) {
        int v = (tid >= off) ? partial[tid - off] : 0;
        __syncthreads();
        partial[tid] += v;
        __syncthreads();
    }
    int run = (tid == 0) ? 0 : partial[tid - 1];   // exclusive
    for (int i = 0; i < PER; ++i) {
        int idx = base + i;
        if (idx < N_NODES) {
            int d = deg_cursor[idx];    // read BEFORE overwrite (aliased)
            row_off[idx] = run;
            deg_cursor[idx] = run;      // becomes fill cursor
            run += d;
        }
    }
    if (tid == 1023) row_off[N_NODES] = run;  // covers all nodes (base >= N)
}

// ---------------- CSR fill ----------------
__global__ void sage_fill_kernel(const int* __restrict__ src, const int* __restrict__ dst,
                                 int* __restrict__ cursor, int* __restrict__ csr) {
    int e = blockIdx.x * blockDim.x + threadIdx.x;
    if (e >= N_EDGES) return;
    int pos = atomicAdd(&cursor[dst[e]], 1);
    csr[pos] = src[e];
}

// ---------------- gather-aggregate + mean normalize ----------------
// one wave per node: 64 lanes x float4 = 256 feats
__global__ __launch_bounds__(256)
void sage_gather_kernel(const float* __restrict__ feat,
                        const int* __restrict__ row_off,
                        const int* __restrict__ csr,
                        float* __restrict__ agg) {
    const int node = blockIdx.x * 4 + (threadIdx.x >> 6);
    const int c = threadIdx.x & 63;
    if (node >= N_NODES) return;
    const int k0 = row_off[node];
    const int k1 = row_off[node + 1];
    float4 acc = make_float4(0.f, 0.f, 0.f, 0.f);
    for (int k = k0; k < k1; ++k) {
        const int s = csr[k];   // wave-uniform broadcast
        const float4 v = reinterpret_cast<const float4*>(feat + (size_t)s * D_FEAT)[c];
        acc.x += v.x; acc.y += v.y; acc.z += v.z; acc.w += v.w;
    }
    const float scale = 1.0f / fmaxf((float)(k1 - k0), 1.0f);
    acc.x *= scale; acc.y *= scale; acc.z *= scale; acc.w *= scale;
    reinterpret_cast<float4*>(agg + (size_t)node * D_FEAT)[c] = acc;
}

// ---------------- fused dual GEMM: out = relu?(A1@W1^T + A2@W2^T + bl + br) ----------------
// A1,A2: [N_NODES][256] row-major. W1,W2: [NOUT][256] row-major. Virtual K=512.
// Tiles: BM=64, BN=64, BK=16. 256 threads, 4x4 micro-tile each.
template <bool RELU, int NOUT>
__global__ __launch_bounds__(256)
void sage_gemm_kernel(const float* __restrict__ A1, const float* __restrict__ A2,
                      const float* __restrict__ W1, const float* __restrict__ W2,
                      const float* __restrict__ bl, const float* __restrict__ br,
                      float* __restrict__ out) {
    const int BM = 64, BN = 64, BK = 16;
    __shared__ __align__(16) float As[BK][BM + 4];
    __shared__ __align__(16) float Bs[BK][BN + 4];

    const int tid = threadIdx.x;
    const int tx = tid & 15;
    const int ty = tid >> 4;
    const int row0 = blockIdx.x * BM;
    const int col0 = blockIdx.y * BN;

    const int lr = tid >> 2;
    const int lk = (tid & 3) * 4;

    float acc[4][4] = {};

    for (int kt = 0; kt < 2 * D_FEAT; kt += BK) {
        const float* __restrict__ A = (kt < D_FEAT) ? A1 : A2;
        const float* __restrict__ W = (kt < D_FEAT) ? W1 : W2;
        const int kbase = kt & (D_FEAT - 1);

        {
            const int grow = row0 + lr;
            float4 av = make_float4(0.f, 0.f, 0.f, 0.f);
            if (grow < N_NODES)
                av = *reinterpret_cast<const float4*>(A + (size_t)grow * D_FEAT + kbase + lk);
            As[lk + 0][lr] = av.x;
            As[lk + 1][lr] = av.y;
            As[lk + 2][lr] = av.z;
            As[lk + 3][lr] = av.w;
        }
        {
            const int gcol = col0 + lr;
            float4 bv = make_float4(0.f, 0.f, 0.f, 0.f);
            if (gcol < NOUT)
                bv = *reinterpret_cast<const float4*>(W + (size_t)gcol * D_FEAT + kbase + lk);
            Bs[lk + 0][lr] = bv.x;
            Bs[lk + 1][lr] = bv.y;
            Bs[lk + 2][lr] = bv.z;
            Bs[lk + 3][lr] = bv.w;
        }
        __syncthreads();

        #pragma unroll
        for (int k = 0; k < BK; ++k) {
            float a[4], b[4];
            *reinterpret_cast<float4*>(a) = *reinterpret_cast<const float4*>(&As[k][ty * 4]);
            *reinterpret_cast<float4*>(b) = *reinterpret_cast<const float4*>(&Bs[k][tx * 4]);
            #pragma unroll
            for (int i = 0; i < 4; ++i)
                #pragma unroll
                for (int j = 0; j < 4; ++j)
                    acc[i][j] += a[i] * b[j];
        }
        __syncthreads();
    }

    #pragma unroll
    for (int i = 0; i < 4; ++i) {
        const int r = row0 + ty * 4 + i;
        if (r >= N_NODES) continue;
        #pragma unroll
        for (int j = 0; j < 4; ++j) {
            const int c = col0 + tx * 4 + j;
            if (c >= NOUT) continue;
            float v = acc[i][j] + bl[c] + br[c];
            if (RELU) v = fmaxf(v, 0.f);
            out[(size_t)r * NOUT + c] = v;
        }
    }
}

extern "C" void kernel_launch(void* const* d_in, const int* in_sizes, int n_in,
                              void* d_out, int out_size, void* d_ws, size_t ws_size,
                              hipStream_t stream) {
    const float* x    = (const float*)d_in[0];
    const int*   ei   = (const int*)d_in[1];      // [2][E] int
    const float* w1l  = (const float*)d_in[2];
    const float* b1l  = (const float*)d_in[3];
    const float* w1r  = (const float*)d_in[4];
    const float* b1r  = (const float*)d_in[5];
    const float* w2l  = (const float*)d_in[6];
    const float* b2l  = (const float*)d_in[7];
    const float* w2r  = (const float*)d_in[8];
    const float* b2r  = (const float*)d_in[9];
    float* out = (float*)d_out;

    const int* src = ei;
    const int* dst = ei + N_EDGES;

    // workspace layout (bytes)
    const size_t ROW_OFF_OFF = 0;                          // 51200 ints (>= N+1)
    const size_t CURSOR_OFF  = 204800;                     // 50000 ints (deg -> cursor)
    const size_t CSR_OFF     = 409600;                     // 800000 ints
    const size_t AGG_OFF     = CSR_OFF + (size_t)N_EDGES * 4;          // 3,609,600
    const size_t AGG_BYTES   = (size_t)N_NODES * D_FEAT * 4;           // 51.2 MB
    const size_t H_OFF       = AGG_OFF + AGG_BYTES;

    int*   row_off = (int*)((char*)d_ws + ROW_OFF_OFF);
    int*   cursor  = (int*)((char*)d_ws + CURSOR_OFF);
    int*   csr     = (int*)((char*)d_ws + CSR_OFF);
    float* agg     = (float*)((char*)d_ws + AGG_OFF);
    float* h       = (float*)((char*)d_ws + H_OFF);

    const int eblocks = (N_EDGES + 255) / 256;     // 3125
    const int gblocks = (N_NODES + 3) / 4;         // 12500
    const int mblocks = (N_NODES + 63) / 64;       // 782

    // ---- CSR build (shared by both layers) ----
    hipMemsetAsync(cursor, 0, (size_t)N_NODES * 4, stream);
    sage_deg_kernel<<<eblocks, 256, 0, stream>>>(dst, cursor);
    sage_scan_kernel<<<1, 1024, 0, stream>>>(cursor, row_off);
    sage_fill_kernel<<<eblocks, 256, 0, stream>>>(src, dst, cursor, csr);

    // ---- layer 1 ----
    sage_gather_kernel<<<gblocks, 256, 0, stream>>>(x, row_off, csr, agg);
    sage_gemm_kernel<true, D_FEAT><<<dim3(mblocks, D_FEAT / 64), 256, 0, stream>>>(
        agg, x, w1l, w1r, b1l, b1r, h);

    // ---- layer 2 ----
    sage_gather_kernel<<<gblocks, 256, 0, stream>>>(h, row_off, csr, agg);
    sage_gemm_kernel<false, N_CLASS><<<dim3(mblocks, 1), 256, 0, stream>>>(
        agg, h, w2l, w2r, b2l, b2r, out);

    (void)in_sizes; (void)n_in; (void)out_size; (void)ws_size;
}

// Round 3
// 474.856 us; speedup vs baseline: 11.9482x; 1.4868x over previous
//
#include <hip/hip_runtime.h>

#define N_NODES 50000
#define N_EDGES 800000
#define D_FEAT  256
#define N_CLASS 40

typedef __attribute__((ext_vector_type(8))) short short8;
typedef __attribute__((ext_vector_type(4))) float f32x4;

__device__ __forceinline__ float bf2f(unsigned short u) {
    unsigned int x = ((unsigned int)u) << 16;
    return __builtin_bit_cast(float, x);
}
__device__ __forceinline__ unsigned short f2bf(float f) {
    unsigned int x = __builtin_bit_cast(unsigned int, f);
    x += 0x7fff + ((x >> 16) & 1);   // RTNE
    return (unsigned short)(x >> 16);
}
__device__ __forceinline__ void async_copy16(const void* g, void* l) {
    __builtin_amdgcn_global_load_lds(
        (const __attribute__((address_space(1))) void*)g,
        (__attribute__((address_space(3))) void*)l, 16, 0, 0);
}

// ---------------- fp32 -> bf16 convert (n multiple of 4) ----------------
__global__ void cvt_bf16_kernel(const float* __restrict__ in, unsigned short* __restrict__ out, int n4) {
    int i = blockIdx.x * blockDim.x + threadIdx.x;
    if (i >= n4) return;
    float4 v = reinterpret_cast<const float4*>(in)[i];
    ushort4 o;
    o.x = f2bf(v.x); o.y = f2bf(v.y); o.z = f2bf(v.z); o.w = f2bf(v.w);
    reinterpret_cast<ushort4*>(out)[i] = o;
}

// ---------------- degree histogram ----------------
__global__ void sage_deg_kernel(const int* __restrict__ dst, int* __restrict__ degc) {
    int e = blockIdx.x * blockDim.x + threadIdx.x;
    if (e < N_EDGES) atomicAdd(&degc[dst[e]], 1);
}

// ---------------- single-workgroup exclusive scan ----------------
__global__ __launch_bounds__(1024)
void sage_scan_kernel(int* __restrict__ deg_cursor, int* __restrict__ row_off) {
    __shared__ int partial[1024];
    const int tid = threadIdx.x;
    const int PER = (N_NODES + 1023) / 1024;   // 49
    const int base = tid * PER;

    int sum = 0;
    for (int i = 0; i < PER; ++i) {
        int idx = base + i;
        if (idx < N_NODES) sum += deg_cursor[idx];
    }
    partial[tid] = sum;
    __syncthreads();
    for (int off = 1; off < 1024; off <<= 1) {
        int v = (tid >= off) ? partial[tid - off] : 0;
        __syncthreads();
        partial[tid] += v;
        __syncthreads();
    }
    int run = (tid == 0) ? 0 : partial[tid - 1];
    for (int i = 0; i < PER; ++i) {
        int idx = base + i;
        if (idx < N_NODES) {
            int d = deg_cursor[idx];
            row_off[idx] = run;
            deg_cursor[idx] = run;
            run += d;
        }
    }
    if (tid == 1023) row_off[N_NODES] = run;
}

// ---------------- CSR fill ----------------
__global__ void sage_fill_kernel(const int* __restrict__ src, const int* __restrict__ dst,
                                 int* __restrict__ cursor, int* __restrict__ csr) {
    int e = blockIdx.x * blockDim.x + threadIdx.x;
    if (e >= N_EDGES) return;
    int pos = atomicAdd(&cursor[dst[e]], 1);
    csr[pos] = src[e];
}

// ---------------- bf16 gather-aggregate + mean ----------------
// one wave per node: 64 lanes x 4 bf16 = 256 feats (8B/lane loads)
__global__ __launch_bounds__(256)
void sage_gather_kernel(const unsigned short* __restrict__ feat,
                        const int* __restrict__ row_off,
                        const int* __restrict__ csr,
                        unsigned short* __restrict__ agg) {
    const int node = blockIdx.x * 4 + (threadIdx.x >> 6);
    const int c4 = (threadIdx.x & 63) * 4;
    if (node >= N_NODES) return;
    const int k0 = row_off[node];
    const int k1 = row_off[node + 1];
    float a0 = 0.f, a1 = 0.f, a2 = 0.f, a3 = 0.f;
    for (int k = k0; k < k1; ++k) {
        const int s = csr[k];   // wave-uniform
        ushort4 v = *reinterpret_cast<const ushort4*>(feat + (size_t)s * D_FEAT + c4);
        a0 += bf2f(v.x); a1 += bf2f(v.y); a2 += bf2f(v.z); a3 += bf2f(v.w);
    }
    const float sc = 1.0f / fmaxf((float)(k1 - k0), 1.0f);
    ushort4 o;
    o.x = f2bf(a0 * sc); o.y = f2bf(a1 * sc); o.z = f2bf(a2 * sc); o.w = f2bf(a3 * sc);
    *reinterpret_cast<ushort4*>(agg + (size_t)node * D_FEAT + c4) = o;
}

// ---------------- MFMA dual GEMM: out = act(A1@W1^T + A2@W2^T + bl + br) ----------------
// A1,A2: [N_NODES][256] bf16. W1,W2: [NOUT][256] bf16 row-major (B^T form).
// Tile 128x128, BK=32, 4 waves (2x2), each wave 64x64 = 4x4 fragments of 16x16x32.
// A staged in LDS via global_load_lds(16B); B fragments direct from global (L2-hot weights).
template <bool RELU, int NOUT, bool OUT_BF16>
__global__ __launch_bounds__(256)
void sage_mfma_gemm(const unsigned short* __restrict__ A1, const unsigned short* __restrict__ A2,
                    const unsigned short* __restrict__ W1, const unsigned short* __restrict__ W2,
                    const float* __restrict__ bl, const float* __restrict__ br,
                    void* __restrict__ outv) {
    __shared__ unsigned short As[128 * 32];   // 8 KB, linear [row][k] k-contiguous

    const int tid  = threadIdx.x;
    const int wid  = tid >> 6;
    const int lane = tid & 63;
    const int wm = wid >> 1;          // 2x2 wave grid
    const int wn = wid & 1;
    const int l15 = lane & 15;
    const int l4  = lane >> 4;
    const int row0 = blockIdx.x * 128;
    const int col0 = blockIdx.y * 128;

    f32x4 acc[4][4] = {};

    for (int kt = 0; kt < 2 * D_FEAT; kt += 32) {
        const unsigned short* __restrict__ Asrc = (kt < D_FEAT) ? A1 : A2;
        const unsigned short* __restrict__ Wsrc = (kt < D_FEAT) ? W1 : W2;
        const int kk = kt & (D_FEAT - 1);

        // stage A-tile [128][32] bf16 = 512 granules of 16B, linear LDS
        #pragma unroll
        for (int it = 0; it < 2; ++it) {
            const int g = it * 256 + tid;         // granule: row = g>>2, pos = g&3
            int grow = row0 + (g >> 2);
            if (grow > N_NODES - 1) grow = N_NODES - 1;   // clamp (discarded at store)
            const unsigned short* gp = Asrc + (size_t)grow * D_FEAT + kk + (g & 3) * 8;
            unsigned short* lp = As + ((size_t)(it * 256 + wid * 64)) * 8;  // wave-uniform base
            async_copy16(gp, lp);
        }
        __syncthreads();

        // A fragments from LDS
        short8 a[4];
        #pragma unroll
        for (int mi = 0; mi < 4; ++mi)
            a[mi] = *reinterpret_cast<const short8*>(&As[(wm * 64 + mi * 16 + l15) * 32 + l4 * 8]);

        // B fragments direct from global
        short8 b[4];
        #pragma unroll
        for (int ni = 0; ni < 4; ++ni) {
            const int c_ = col0 + wn * 64 + ni * 16 + l15;
            if (NOUT == 256 || c_ < NOUT)
                b[ni] = *reinterpret_cast<const short8*>(Wsrc + (size_t)c_ * D_FEAT + kk + l4 * 8);
            else
                b[ni] = short8{};
        }

        #pragma unroll
        for (int mi = 0; mi < 4; ++mi)
            #pragma unroll
            for (int ni = 0; ni < 4; ++ni)
                acc[mi][ni] = __builtin_amdgcn_mfma_f32_16x16x32_bf16(a[mi], b[ni], acc[mi][ni], 0, 0, 0);

        __syncthreads();
    }

    // epilogue: D layout col=lane&15, row=(lane>>4)*4+i
    #pragma unroll
    for (int ni = 0; ni < 4; ++ni) {
        const int c_ = col0 + wn * 64 + ni * 16 + l15;
        if (NOUT != 256 && c_ >= NOUT) continue;
        const float bias = bl[c_] + br[c_];
        #pragma unroll
        for (int mi = 0; mi < 4; ++mi) {
            #pragma unroll
            for (int i = 0; i < 4; ++i) {
                const int r = row0 + wm * 64 + mi * 16 + l4 * 4 + i;
                if (r >= N_NODES) continue;
                float v = acc[mi][ni][i] + bias;
                if (RELU) v = fmaxf(v, 0.f);
                if (OUT_BF16)
                    ((unsigned short*)outv)[(size_t)r * NOUT + c_] = f2bf(v);
                else
                    ((float*)outv)[(size_t)r * NOUT + c_] = v;
            }
        }
    }
}

extern "C" void kernel_launch(void* const* d_in, const int* in_sizes, int n_in,
                              void* d_out, int out_size, void* d_ws, size_t ws_size,
                              hipStream_t stream) {
    const float* x    = (const float*)d_in[0];
    const int*   ei   = (const int*)d_in[1];
    const float* w1l  = (const float*)d_in[2];
    const float* b1l  = (const float*)d_in[3];
    const float* w1r  = (const float*)d_in[4];
    const float* b1r  = (const float*)d_in[5];
    const float* w2l  = (const float*)d_in[6];
    const float* b2l  = (const float*)d_in[7];
    const float* w2r  = (const float*)d_in[8];
    const float* b2r  = (const float*)d_in[9];
    float* out = (float*)d_out;

    const int* src = ei;
    const int* dst = ei + N_EDGES;

    // workspace layout (bytes, 64-aligned)
    const size_t ROW_OFF_OFF = 0;          // 50001 ints
    const size_t CURSOR_OFF  = 204800;     // 50000 ints
    const size_t CSR_OFF     = 409600;     // 800000 ints -> ends 3,609,600
    const size_t XB_OFF      = 3612672;
    const size_t FEAT_BYTES  = (size_t)N_NODES * D_FEAT * 2;   // 25.6 MB
    const size_t AGG_OFF     = XB_OFF + FEAT_BYTES;
    const size_t H_OFF       = AGG_OFF + FEAT_BYTES;
    const size_t W1L_OFF     = H_OFF + FEAT_BYTES;
    const size_t W1R_OFF     = W1L_OFF + 131072;
    const size_t W2L_OFF     = W1R_OFF + 131072;
    const size_t W2R_OFF     = W2L_OFF + 20480;

    int* row_off = (int*)((char*)d_ws + ROW_OFF_OFF);
    int* cursor  = (int*)((char*)d_ws + CURSOR_OFF);
    int* csr     = (int*)((char*)d_ws + CSR_OFF);
    unsigned short* xb   = (unsigned short*)((char*)d_ws + XB_OFF);
    unsigned short* aggb = (unsigned short*)((char*)d_ws + AGG_OFF);
    unsigned short* hb   = (unsigned short*)((char*)d_ws + H_OFF);
    unsigned short* w1lb = (unsigned short*)((char*)d_ws + W1L_OFF);
    unsigned short* w1rb = (unsigned short*)((char*)d_ws + W1R_OFF);
    unsigned short* w2lb = (unsigned short*)((char*)d_ws + W2L_OFF);
    unsigned short* w2rb = (unsigned short*)((char*)d_ws + W2R_OFF);

    const int eblocks = (N_EDGES + 255) / 256;
    const int gblocks = (N_NODES + 3) / 4;
    const int mblocks = (N_NODES + 127) / 128;   // 391

    // ---- converts ----
    cvt_bf16_kernel<<<(N_NODES * D_FEAT / 4 + 255) / 256, 256, 0, stream>>>(x, xb, N_NODES * D_FEAT / 4);
    cvt_bf16_kernel<<<64, 256, 0, stream>>>(w1l, w1lb, D_FEAT * D_FEAT / 4);
    cvt_bf16_kernel<<<64, 256, 0, stream>>>(w1r, w1rb, D_FEAT * D_FEAT / 4);
    cvt_bf16_kernel<<<10, 256, 0, stream>>>(w2l, w2lb, N_CLASS * D_FEAT / 4);
    cvt_bf16_kernel<<<10, 256, 0, stream>>>(w2r, w2rb, N_CLASS * D_FEAT / 4);

    // ---- CSR build ----
    hipMemsetAsync(cursor, 0, (size_t)N_NODES * 4, stream);
    sage_deg_kernel<<<eblocks, 256, 0, stream>>>(dst, cursor);
    sage_scan_kernel<<<1, 1024, 0, stream>>>(cursor, row_off);
    sage_fill_kernel<<<eblocks, 256, 0, stream>>>(src, dst, cursor, csr);

    // ---- layer 1 ----
    sage_gather_kernel<<<gblocks, 256, 0, stream>>>(xb, row_off, csr, aggb);
    sage_mfma_gemm<true, D_FEAT, true><<<dim3(mblocks, 2), 256, 0, stream>>>(
        aggb, xb, w1lb, w1rb, b1l, b1r, hb);

    // ---- layer 2 ----
    sage_gather_kernel<<<gblocks, 256, 0, stream>>>(hb, row_off, csr, aggb);
    sage_mfma_gemm<false, N_CLASS, false><<<dim3(mblocks, 1), 256, 0, stream>>>(
        aggb, hb, w2lb, w2rb, b2l, b2r, out);

    (void)in_sizes; (void)n_in; (void)out_size; (void)ws_size;
}

// Round 4
// 312.120 us; speedup vs baseline: 18.1779x; 1.5214x over previous
//
#include <hip/hip_runtime.h>

#define N_NODES 50000
#define N_EDGES 800000
#define D_FEAT  256
#define N_CLASS 40
#define NSCAN_BLOCKS ((N_NODES + 255) / 256)   // 196

typedef __attribute__((ext_vector_type(8))) short short8;
typedef __attribute__((ext_vector_type(4))) float f32x4;

__device__ __forceinline__ float bf2f(unsigned short u) {
    unsigned int x = ((unsigned int)u) << 16;
    return __builtin_bit_cast(float, x);
}
__device__ __forceinline__ unsigned short f2bf(float f) {
    unsigned int x = __builtin_bit_cast(unsigned int, f);
    x += 0x7fff + ((x >> 16) & 1);   // RTNE
    return (unsigned short)(x >> 16);
}
__device__ __forceinline__ void async_copy16(const void* g, void* l) {
    __builtin_amdgcn_global_load_lds(
        (const __attribute__((address_space(1))) void*)g,
        (__attribute__((address_space(3))) void*)l, 16, 0, 0);
}

// ---------------- fp32 -> bf16 convert (x) ----------------
__global__ void cvt_bf16_kernel(const float* __restrict__ in, unsigned short* __restrict__ out, int n4) {
    int i = blockIdx.x * blockDim.x + threadIdx.x;
    if (i >= n4) return;
    float4 v = reinterpret_cast<const float4*>(in)[i];
    ushort4 o;
    o.x = f2bf(v.x); o.y = f2bf(v.y); o.z = f2bf(v.z); o.w = f2bf(v.w);
    reinterpret_cast<ushort4*>(out)[i] = o;
}

// ---------------- fused weight converts (4 matrices, one dispatch) ----------------
__global__ void cvt_weights_kernel(const float* __restrict__ w1l, const float* __restrict__ w1r,
                                   const float* __restrict__ w2l, const float* __restrict__ w2r,
                                   unsigned short* __restrict__ o1l, unsigned short* __restrict__ o1r,
                                   unsigned short* __restrict__ o2l, unsigned short* __restrict__ o2r) {
    int i = blockIdx.x * blockDim.x + threadIdx.x;   // float4 index
    const int A = D_FEAT * D_FEAT / 4;               // 16384
    const int B = 2 * A;                             // 32768
    const int C = B + N_CLASS * D_FEAT / 4;          // 35328
    const int D = C + N_CLASS * D_FEAT / 4;          // 37888
    const float* src; unsigned short* dst; int off;
    if      (i < A) { src = w1l; dst = o1l; off = i; }
    else if (i < B) { src = w1r; dst = o1r; off = i - A; }
    else if (i < C) { src = w2l; dst = o2l; off = i - B; }
    else if (i < D) { src = w2r; dst = o2r; off = i - C; }
    else return;
    float4 v = reinterpret_cast<const float4*>(src)[off];
    ushort4 o;
    o.x = f2bf(v.x); o.y = f2bf(v.y); o.z = f2bf(v.z); o.w = f2bf(v.w);
    reinterpret_cast<ushort4*>(dst)[off] = o;
}

// ---------------- degree histogram ----------------
__global__ void sage_deg_kernel(const int* __restrict__ dst, int* __restrict__ degc) {
    int e = blockIdx.x * blockDim.x + threadIdx.x;
    if (e < N_EDGES) atomicAdd(&degc[dst[e]], 1);
}

// ---------------- hierarchical scan: phase 1 (per-block exclusive scan + block sum) ----------------
__global__ __launch_bounds__(256)
void scan_local_kernel(const int* __restrict__ deg, int* __restrict__ escan, int* __restrict__ bsum) {
    __shared__ int s[256];
    const int t = threadIdx.x;
    const int i = blockIdx.x * 256 + t;
    const int v = (i < N_NODES) ? deg[i] : 0;
    s[t] = v;
    __syncthreads();
    #pragma unroll
    for (int off = 1; off < 256; off <<= 1) {
        int u = (t >= off) ? s[t - off] : 0;
        __syncthreads();
        s[t] += u;
        __syncthreads();
    }
    if (i < N_NODES) escan[i] = s[t] - v;        // in-block exclusive
    if (t == 255) bsum[blockIdx.x] = s[255];     // block total
}

// ---------------- scan phase 2: scan the 196 block sums ----------------
__global__ __launch_bounds__(256)
void scan_bsum_kernel(int* __restrict__ bsum, int* __restrict__ row_off) {
    __shared__ int s[256];
    const int t = threadIdx.x;
    const int v = (t < NSCAN_BLOCKS) ? bsum[t] : 0;
    s[t] = v;
    __syncthreads();
    #pragma unroll
    for (int off = 1; off < 256; off <<= 1) {
        int u = (t >= off) ? s[t - off] : 0;
        __syncthreads();
        s[t] += u;
        __syncthreads();
    }
    if (t < NSCAN_BLOCKS) bsum[t] = s[t] - v;    // exclusive block offsets
    if (t == 255) row_off[N_NODES] = s[255];     // grand total (= N_EDGES)
}

// ---------------- scan phase 3: add block offsets -> row_off & cursor ----------------
__global__ void scan_add_kernel(const int* __restrict__ escan_in, const int* __restrict__ bsum,
                                int* __restrict__ row_off, int* __restrict__ cursor) {
    const int i = blockIdx.x * 256 + threadIdx.x;
    if (i >= N_NODES) return;
    const int v = escan_in[i] + bsum[blockIdx.x];
    row_off[i] = v;
    cursor[i] = v;
}

// ---------------- CSR fill ----------------
__global__ void sage_fill_kernel(const int* __restrict__ src, const int* __restrict__ dst,
                                 int* __restrict__ cursor, int* __restrict__ csr) {
    int e = blockIdx.x * blockDim.x + threadIdx.x;
    if (e >= N_EDGES) return;
    int pos = atomicAdd(&cursor[dst[e]], 1);
    csr[pos] = src[e];
}

// ---------------- bf16 gather-aggregate + mean ----------------
// 2 nodes per wave: 32 lanes x 8 bf16 (16B) = 256 feats per node
__global__ __launch_bounds__(256)
void sage_gather_kernel(const unsigned short* __restrict__ feat,
                        const int* __restrict__ row_off,
                        const int* __restrict__ csr,
                        unsigned short* __restrict__ agg) {
    const int tid = threadIdx.x;
    const int lane = tid & 63;
    const int node = blockIdx.x * 8 + (tid >> 6) * 2 + (lane >> 5);
    const int c8 = (lane & 31) * 8;
    if (node >= N_NODES) return;
    const int k0 = row_off[node];
    const int k1 = row_off[node + 1];
    float a[8] = {};
    for (int k = k0; k < k1; ++k) {
        const int s = csr[k];   // uniform per half-wave
        short8 v = *reinterpret_cast<const short8*>(feat + (size_t)s * D_FEAT + c8);
        #pragma unroll
        for (int j = 0; j < 8; ++j) a[j] += bf2f((unsigned short)v[j]);
    }
    const float sc = 1.0f / fmaxf((float)(k1 - k0), 1.0f);
    short8 o;
    #pragma unroll
    for (int j = 0; j < 8; ++j) o[j] = (short)f2bf(a[j] * sc);
    *reinterpret_cast<short8*>(agg + (size_t)node * D_FEAT + c8) = o;
}

// ---------------- MFMA dual GEMM: out = act(A1@W1^T + A2@W2^T + bl + br) ----------------
// Tile 128x128, BK=32, 4 waves (2x2), each wave 64x64 = 4x4 fragments of 16x16x32.
template <bool RELU, int NOUT, bool OUT_BF16>
__global__ __launch_bounds__(256)
void sage_mfma_gemm(const unsigned short* __restrict__ A1, const unsigned short* __restrict__ A2,
                    const unsigned short* __restrict__ W1, const unsigned short* __restrict__ W2,
                    const float* __restrict__ bl, const float* __restrict__ br,
                    void* __restrict__ outv) {
    __shared__ unsigned short As[128 * 32];   // 8 KB, linear [row][k] k-contiguous

    const int tid  = threadIdx.x;
    const int wid  = tid >> 6;
    const int lane = tid & 63;
    const int wm = wid >> 1;
    const int wn = wid & 1;
    const int l15 = lane & 15;
    const int l4  = lane >> 4;
    const int row0 = blockIdx.x * 128;
    const int col0 = blockIdx.y * 128;

    f32x4 acc[4][4] = {};

    for (int kt = 0; kt < 2 * D_FEAT; kt += 32) {
        const unsigned short* __restrict__ Asrc = (kt < D_FEAT) ? A1 : A2;
        const unsigned short* __restrict__ Wsrc = (kt < D_FEAT) ? W1 : W2;
        const int kk = kt & (D_FEAT - 1);

        #pragma unroll
        for (int it = 0; it < 2; ++it) {
            const int g = it * 256 + tid;
            int grow = row0 + (g >> 2);
            if (grow > N_NODES - 1) grow = N_NODES - 1;
            const unsigned short* gp = Asrc + (size_t)grow * D_FEAT + kk + (g & 3) * 8;
            unsigned short* lp = As + ((size_t)(it * 256 + wid * 64)) * 8;
            async_copy16(gp, lp);
        }
        __syncthreads();

        short8 a[4];
        #pragma unroll
        for (int mi = 0; mi < 4; ++mi)
            a[mi] = *reinterpret_cast<const short8*>(&As[(wm * 64 + mi * 16 + l15) * 32 + l4 * 8]);

        short8 b[4];
        #pragma unroll
        for (int ni = 0; ni < 4; ++ni) {
            const int c_ = col0 + wn * 64 + ni * 16 + l15;
            if (NOUT == 256 || c_ < NOUT)
                b[ni] = *reinterpret_cast<const short8*>(Wsrc + (size_t)c_ * D_FEAT + kk + l4 * 8);
            else
                b[ni] = short8{};
        }

        #pragma unroll
        for (int mi = 0; mi < 4; ++mi)
            #pragma unroll
            for (int ni = 0; ni < 4; ++ni)
                acc[mi][ni] = __builtin_amdgcn_mfma_f32_16x16x32_bf16(a[mi], b[ni], acc[mi][ni], 0, 0, 0);

        __syncthreads();
    }

    #pragma unroll
    for (int ni = 0; ni < 4; ++ni) {
        const int c_ = col0 + wn * 64 + ni * 16 + l15;
        if (NOUT != 256 && c_ >= NOUT) continue;
        const float bias = bl[c_] + br[c_];
        #pragma unroll
        for (int mi = 0; mi < 4; ++mi) {
            #pragma unroll
            for (int i = 0; i < 4; ++i) {
                const int r = row0 + wm * 64 + mi * 16 + l4 * 4 + i;
                if (r >= N_NODES) continue;
                float v = acc[mi][ni][i] + bias;
                if (RELU) v = fmaxf(v, 0.f);
                if (OUT_BF16)
                    ((unsigned short*)outv)[(size_t)r * NOUT + c_] = f2bf(v);
                else
                    ((float*)outv)[(size_t)r * NOUT + c_] = v;
            }
        }
    }
}

extern "C" void kernel_launch(void* const* d_in, const int* in_sizes, int n_in,
                              void* d_out, int out_size, void* d_ws, size_t ws_size,
                              hipStream_t stream) {
    const float* x    = (const float*)d_in[0];
    const int*   ei   = (const int*)d_in[1];
    const float* w1l  = (const float*)d_in[2];
    const float* b1l  = (const float*)d_in[3];
    const float* w1r  = (const float*)d_in[4];
    const float* b1r  = (const float*)d_in[5];
    const float* w2l  = (const float*)d_in[6];
    const float* b2l  = (const float*)d_in[7];
    const float* w2r  = (const float*)d_in[8];
    const float* b2r  = (const float*)d_in[9];
    float* out = (float*)d_out;

    const int* src = ei;
    const int* dst = ei + N_EDGES;

    // workspace layout (bytes)
    const size_t ROW_OFF_OFF = 0;          // 50001 ints
    const size_t CURSOR_OFF  = 204800;     // 50000 ints (deg -> cursor)
    const size_t BSUM_OFF    = 409600;     // 256 ints
    const size_t CSR_OFF     = 410624;     // 800000 ints
    const size_t XB_OFF      = CSR_OFF + (size_t)N_EDGES * 4 + 1024;   // 3,611,648
    const size_t FEAT_BYTES  = (size_t)N_NODES * D_FEAT * 2;           // 25.6 MB
    const size_t AGG_OFF     = XB_OFF + FEAT_BYTES;
    const size_t H_OFF       = AGG_OFF + FEAT_BYTES;
    const size_t W1L_OFF     = H_OFF + FEAT_BYTES;
    const size_t W1R_OFF     = W1L_OFF + 131072;
    const size_t W2L_OFF     = W1R_OFF + 131072;
    const size_t W2R_OFF     = W2L_OFF + 20480;

    int* row_off = (int*)((char*)d_ws + ROW_OFF_OFF);
    int* cursor  = (int*)((char*)d_ws + CURSOR_OFF);
    int* bsum    = (int*)((char*)d_ws + BSUM_OFF);
    int* csr     = (int*)((char*)d_ws + CSR_OFF);
    unsigned short* xb   = (unsigned short*)((char*)d_ws + XB_OFF);
    unsigned short* aggb = (unsigned short*)((char*)d_ws + AGG_OFF);
    unsigned short* hb   = (unsigned short*)((char*)d_ws + H_OFF);
    unsigned short* w1lb = (unsigned short*)((char*)d_ws + W1L_OFF);
    unsigned short* w1rb = (unsigned short*)((char*)d_ws + W1R_OFF);
    unsigned short* w2lb = (unsigned short*)((char*)d_ws + W2L_OFF);
    unsigned short* w2rb = (unsigned short*)((char*)d_ws + W2R_OFF);

    const int eblocks = (N_EDGES + 255) / 256;     // 3125
    const int gblocks = (N_NODES + 7) / 8;         // 6250
    const int mblocks = (N_NODES + 127) / 128;     // 391

    // ---- converts ----
    cvt_bf16_kernel<<<(N_NODES * D_FEAT / 4 + 255) / 256, 256, 0, stream>>>(x, xb, N_NODES * D_FEAT / 4);
    cvt_weights_kernel<<<148, 256, 0, stream>>>(w1l, w1r, w2l, w2r, w1lb, w1rb, w2lb, w2rb);

    // ---- CSR build ----
    hipMemsetAsync(cursor, 0, (size_t)N_NODES * 4, stream);
    sage_deg_kernel<<<eblocks, 256, 0, stream>>>(dst, cursor);
    scan_local_kernel<<<NSCAN_BLOCKS, 256, 0, stream>>>(cursor, row_off, bsum);
    scan_bsum_kernel<<<1, 256, 0, stream>>>(bsum, row_off);
    scan_add_kernel<<<NSCAN_BLOCKS, 256, 0, stream>>>(row_off, bsum, row_off, cursor);
    sage_fill_kernel<<<eblocks, 256, 0, stream>>>(src, dst, cursor, csr);

    // ---- layer 1 ----
    sage_gather_kernel<<<gblocks, 256, 0, stream>>>(xb, row_off, csr, aggb);
    sage_mfma_gemm<true, D_FEAT, true><<<dim3(mblocks, 2), 256, 0, stream>>>(
        aggb, xb, w1lb, w1rb, b1l, b1r, hb);

    // ---- layer 2 ----
    sage_gather_kernel<<<gblocks, 256, 0, stream>>>(hb, row_off, csr, aggb);
    sage_mfma_gemm<false, N_CLASS, false><<<dim3(mblocks, 1), 256, 0, stream>>>(
        aggb, hb, w2lb, w2rb, b2l, b2r, out);

    (void)in_sizes; (void)n_in; (void)out_size; (void)ws_size;
}